// Round 4
// baseline (236.007 us; speedup 1.0000x reference)
//
#include <hip/hip_runtime.h>
#include <cstdint>
#include <cstddef>

#define Bb 8
#define Ss 2048
#define Dd 512

typedef _Float16 half8 __attribute__((ext_vector_type(8)));
typedef _Float16 half4_ __attribute__((ext_vector_type(4)));
typedef _Float16 half2_t __attribute__((ext_vector_type(2)));
typedef float f32x4 __attribute__((ext_vector_type(4)));

static __device__ __forceinline__ void gload_lds16(const void* g, void* l) {
  __builtin_amdgcn_global_load_lds((const __attribute__((address_space(1))) void*)g,
                                   (__attribute__((address_space(3))) void*)l,
                                   16, 0, 0);
}

// ---------------- K0a: fp32 -> fp16 bulk convert (dec) ----------------
__global__ void k0_cvt(const float* __restrict__ in, _Float16* __restrict__ out, int n8) {
  int i = blockIdx.x * blockDim.x + threadIdx.x;
  if (i >= n8) return;
  const float4* p = (const float4*)in + (size_t)i * 2;
  float4 a = p[0], b = p[1];
  half8 h;
  h[0] = (_Float16)a.x; h[1] = (_Float16)a.y; h[2] = (_Float16)a.z; h[3] = (_Float16)a.w;
  h[4] = (_Float16)b.x; h[5] = (_Float16)b.y; h[6] = (_Float16)b.z; h[7] = (_Float16)b.w;
  *(half8*)(out + (size_t)i * 8) = h;
}

// ---------------- K0b: enc fp32 -> enc16 (row-major) + encT (transposed) ----------------
__global__ void k0_enc(const float* __restrict__ enc, _Float16* __restrict__ enc16,
                       _Float16* __restrict__ encT) {
  __shared__ float tile[32][33];
  int bid = blockIdx.x;
  int b = bid & 7, kt = (bid >> 3) & 63, dt = bid >> 9;  // 8 * 64 * 16 blocks
  int key0 = kt * 32, d0 = dt * 32;
  int t = threadIdx.x;
  const float* src = enc + ((size_t)b * Ss + key0) * Dd + d0;
  _Float16* dst = enc16 + ((size_t)b * Ss + key0) * Dd + d0;
#pragma unroll
  for (int p = 0; p < 4; ++p) {
    int idx = t + p * 256;
    int r = idx >> 5, c = idx & 31;
    float v = src[(size_t)r * Dd + c];
    tile[r][c] = v;
    dst[(size_t)r * Dd + c] = (_Float16)v;
  }
  __syncthreads();
  {
    int dr = t >> 3, kq = t & 7;  // 32 d-rows x 8 key-quads
    _Float16* o = encT + ((size_t)b * Dd + d0 + dr) * Ss + key0 + kq * 4;
    half4_ v;
#pragma unroll
    for (int j = 0; j < 4; ++j) v[j] = (_Float16)tile[kq * 4 + j][dr];
    *(half4_*)o = v;
  }
}

// ---------------- K1: S_unnorm = exp(dec16 @ enc16^T - m_chunk)  + chunk stats ----------------
// launch_bounds (256,4): 4 blocks/CU resident (LDS 32KB allows 5; 60 VGPR + 64 AGPR = 124 <= 128 cap)
__launch_bounds__(256, 4)
__global__ void k1_qk(const _Float16* __restrict__ A, const _Float16* __restrict__ Bm,
                      _Float16* __restrict__ S, half2_t* __restrict__ pms) {
  __shared__ __align__(16) _Float16 lA[128 * 64];
  __shared__ __align__(16) _Float16 lB[128 * 64];
  int bid = blockIdx.x;
  int b = bid & 7;
  int t = bid >> 3;
  int tm = t & 15, tn = t >> 4;  // 16 x 16 tiles of 128
  int tid = threadIdx.x;
  int w = tid >> 6, L = tid & 63;
  int wm = w & 1, wn = w >> 1;

  const _Float16* Ag = A + ((size_t)b * Ss + (size_t)tm * 128) * Dd;
  const _Float16* Bg = Bm + ((size_t)b * Ss + (size_t)tn * 128) * Dd;

  int rowS[4], colS[4], ldsOff[4];
#pragma unroll
  for (int i = 0; i < 4; ++i) {
    int se = (w * 4 + i) * 512 + L * 8;  // linear f16 slot
    int row = se >> 6;
    int blk = (se >> 3) & 7;
    rowS[i] = row;
    colS[i] = (blk ^ (row & 7)) << 3;
    ldsOff[i] = se;
  }

  f32x4 acc[4][4];
#pragma unroll
  for (int mt = 0; mt < 4; ++mt)
#pragma unroll
    for (int nt = 0; nt < 4; ++nt) acc[mt][nt] = (f32x4){0.f, 0.f, 0.f, 0.f};

  int g = L >> 4, lm = L & 15;

  for (int k0 = 0; k0 < Dd; k0 += 64) {
    __syncthreads();
#pragma unroll
    for (int i = 0; i < 4; ++i) {
      gload_lds16(Ag + (size_t)rowS[i] * Dd + k0 + colS[i], lA + ldsOff[i]);
      gload_lds16(Bg + (size_t)rowS[i] * Dd + k0 + colS[i], lB + ldsOff[i]);
    }
    __syncthreads();
#pragma unroll
    for (int ds = 0; ds < 64; ds += 32) {
      half8 af[4], bf[4];
#pragma unroll
      for (int mt = 0; mt < 4; ++mt) {
        int row = wm * 64 + mt * 16 + lm;
        int blk = ((ds >> 3) + g) ^ (row & 7);
        af[mt] = *(const half8*)(lA + row * 64 + blk * 8);
      }
#pragma unroll
      for (int nt = 0; nt < 4; ++nt) {
        int row = wn * 64 + nt * 16 + lm;
        int blk = ((ds >> 3) + g) ^ (row & 7);
        bf[nt] = *(const half8*)(lB + row * 64 + blk * 8);
      }
#pragma unroll
      for (int mt = 0; mt < 4; ++mt)
#pragma unroll
        for (int nt = 0; nt < 4; ++nt)
          acc[mt][nt] = __builtin_amdgcn_mfma_f32_16x16x32_f16(af[mt], bf[nt], acc[mt][nt], 0, 0, 0);
    }
  }

  // epilogue: per (row, 64-col chunk) max + exp + sum; store e = exp(s - m_c) as f16
  size_t rowbase = (size_t)b * Ss;
#pragma unroll
  for (int mt = 0; mt < 4; ++mt) {
#pragma unroll
    for (int r = 0; r < 4; ++r) {
      int row_g = tm * 128 + wm * 64 + mt * 16 + g * 4 + r;
      _Float16* Srow = S + (rowbase + row_g) * Ss + (size_t)tn * 128 + wn * 64 + lm;
      float rm = -1e30f;
#pragma unroll
      for (int nt = 0; nt < 4; ++nt) rm = fmaxf(rm, acc[mt][nt][r]);
      rm = fmaxf(rm, __shfl_xor(rm, 1));
      rm = fmaxf(rm, __shfl_xor(rm, 2));
      rm = fmaxf(rm, __shfl_xor(rm, 4));
      rm = fmaxf(rm, __shfl_xor(rm, 8));
      _Float16 mh = (_Float16)rm;   // f16-rounded chunk max; SAME value used in k2_factors
      float mf = (float)mh;
      float sum = 0.f;
#pragma unroll
      for (int nt = 0; nt < 4; ++nt) {
        float e = __expf(acc[mt][nt][r] - mf);
        Srow[nt * 16] = (_Float16)e;
        sum += e;
      }
      sum += __shfl_xor(sum, 1);
      sum += __shfl_xor(sum, 2);
      sum += __shfl_xor(sum, 4);
      sum += __shfl_xor(sum, 8);
      if (lm == 0) {
        half2_t st; st.x = mh; st.y = (_Float16)sum;
        pms[(rowbase + row_g) * 32 + tn * 2 + wn] = st;
      }
    }
  }
}

// ---------------- K2b: per-row global reduce of 32 chunk stats -> per-chunk factor ----------------
// fct layout: [chunk 0..31][row 0..16383] (coalesced for K3's reads)
__global__ void k2_factors(const half2_t* __restrict__ pms, float* __restrict__ fct) {
  int t = threadIdx.x;
  size_t row = (size_t)blockIdx.x * 8 + (t >> 5);  // 8 rows/block, 32 lanes/row
  int c = t & 31;
  half2_t v = pms[row * 32 + c];
  float mc = (float)v.x, sc = (float)v.y;
  float m = mc;
#pragma unroll
  for (int d = 1; d <= 16; d <<= 1) m = fmaxf(m, __shfl_xor(m, d));
  float tot = sc * __expf(mc - m);
#pragma unroll
  for (int d = 1; d <= 16; d <<= 1) tot += __shfl_xor(tot, d);
  fct[(size_t)c * (Bb * Ss) + row] = __expf(mc - m) / tot;
}

// ---------------- K3: C = (e .* factor) @ V ----------------
// 512 threads (8 waves) on a 128x128 tile: waves 2(m) x 4(n), each 64 rows x 32 cols.
// Grid 512 blocks @ 2 blocks/CU -> 16 waves/CU (50% occupancy) vs 25% at 256 threads.
__launch_bounds__(512, 4)
__global__ void k3_pv(const _Float16* __restrict__ P, const _Float16* __restrict__ Vt,
                      const float* __restrict__ fct, float* __restrict__ C) {
  __shared__ __align__(16) _Float16 lA[128 * 64];
  __shared__ __align__(16) _Float16 lB[128 * 64];
  int bid = blockIdx.x;
  int b = bid & 7;
  int t = bid >> 3;
  int tm = t & 15, tn = t >> 4;  // 16 m-tiles, 4 n-tiles (128x128)
  int tid = threadIdx.x;
  int w = tid >> 6, L = tid & 63;
  int wm = w & 1, wn = w >> 1;   // wn in 0..3 -> 32-col slice

  const _Float16* Ag = P + ((size_t)b * Ss + (size_t)tm * 128) * Ss;   // pitch 2048
  const _Float16* Bg = Vt + ((size_t)b * Dd + (size_t)tn * 128) * Ss;  // pitch 2048

  // staging: 4 x 16B per thread (i=0,1 -> lA; i=2,3 -> lB); lane-linear per wave
  int rowS[4], colS[4], ldsOff[4];
#pragma unroll
  for (int i = 0; i < 4; ++i) {
    int slot = (i & 1) * 512 + tid;  // 1024 16B-slots per array
    int se = slot * 8;               // f16 index
    int row = se >> 6;
    int blk = (se >> 3) & 7;
    rowS[i] = row;
    colS[i] = (blk ^ (row & 7)) << 3;
    ldsOff[i] = se;
  }

  f32x4 acc[4][2];
#pragma unroll
  for (int mt = 0; mt < 4; ++mt)
#pragma unroll
    for (int nt = 0; nt < 2; ++nt) acc[mt][nt] = (f32x4){0.f, 0.f, 0.f, 0.f};

  int g = L >> 4, lm = L & 15;
  const float* fbase = fct + (size_t)b * Ss + (size_t)tm * 128 + wm * 64 + lm;

  for (int k0 = 0; k0 < Ss; k0 += 64) {
    __syncthreads();
    gload_lds16(Ag + (size_t)rowS[0] * Ss + k0 + colS[0], lA + ldsOff[0]);
    gload_lds16(Ag + (size_t)rowS[1] * Ss + k0 + colS[1], lA + ldsOff[1]);
    gload_lds16(Bg + (size_t)rowS[2] * Ss + k0 + colS[2], lB + ldsOff[2]);
    gload_lds16(Bg + (size_t)rowS[3] * Ss + k0 + colS[3], lB + ldsOff[3]);
    // chunk factors for this k0 (16 distinct floats per wave, L2-resident)
    _Float16 fh[4];
#pragma unroll
    for (int mt = 0; mt < 4; ++mt)
      fh[mt] = (_Float16)fbase[(size_t)(k0 >> 6) * (Bb * Ss) + mt * 16];
    __syncthreads();
#pragma unroll
    for (int ds = 0; ds < 64; ds += 32) {
      half8 af[4], bf[2];
#pragma unroll
      for (int mt = 0; mt < 4; ++mt) {
        int row = wm * 64 + mt * 16 + lm;
        int blk = ((ds >> 3) + g) ^ (row & 7);
        af[mt] = *(const half8*)(lA + row * 64 + blk * 8);
#pragma unroll
        for (int j = 0; j < 8; ++j) af[mt][j] *= fh[mt];
      }
#pragma unroll
      for (int nt = 0; nt < 2; ++nt) {
        int row = wn * 32 + nt * 16 + lm;
        int blk = ((ds >> 3) + g) ^ (row & 7);
        bf[nt] = *(const half8*)(lB + row * 64 + blk * 8);
      }
#pragma unroll
      for (int mt = 0; mt < 4; ++mt)
#pragma unroll
        for (int nt = 0; nt < 2; ++nt)
          acc[mt][nt] = __builtin_amdgcn_mfma_f32_16x16x32_f16(af[mt], bf[nt], acc[mt][nt], 0, 0, 0);
    }
  }

  // epilogue: fp32 store to output
#pragma unroll
  for (int mt = 0; mt < 4; ++mt) {
#pragma unroll
    for (int r = 0; r < 4; ++r) {
      int row_g = tm * 128 + wm * 64 + mt * 16 + g * 4 + r;
      float* Crow = C + ((size_t)b * Ss + row_g) * Dd + (size_t)tn * 128 + wn * 32 + lm;
#pragma unroll
      for (int nt = 0; nt < 2; ++nt) Crow[nt * 16] = acc[mt][nt][r];
    }
  }
}

extern "C" void kernel_launch(void* const* d_in, const int* in_sizes, int n_in,
                              void* d_out, int out_size, void* d_ws, size_t ws_size,
                              hipStream_t stream) {
  const float* enc = (const float*)d_in[0];  // enc_outputs [8][2048][512]
  const float* dec = (const float*)d_in[1];  // dec_outputs [8][2048][512]
  float* out = (float*)d_out;                // [8][2048][512] fp32

  const size_t nElem = (size_t)Bb * Ss * Dd;  // 8388608
  const size_t nS = (size_t)Bb * Ss * Ss;     // 33554432

  _Float16* dec16 = (_Float16*)d_ws;
  _Float16* enc16 = dec16 + nElem;
  _Float16* encT = enc16 + nElem;
  _Float16* Sp = encT + nElem;
  half2_t* pms = (half2_t*)(Sp + nS);         // [16384 rows][32 chunks] half2 = 2 MB
  float* fct = (float*)dec16;                 // aliases dec16 (dead after K1): [32][16384] f32

  size_t need = nElem * 2 * 3 + nS * 2 + (size_t)Bb * Ss * 32 * 4;
  if (ws_size < need) return;

  k0_cvt<<<(int)(nElem / 8 / 256), 256, 0, stream>>>(dec, dec16, (int)(nElem / 8));
  k0_enc<<<8 * 64 * 16, 256, 0, stream>>>(enc, enc16, encT);
  k1_qk<<<2048, 256, 0, stream>>>(dec16, enc16, Sp, pms);
  k2_factors<<<2048, 256, 0, stream>>>(pms, fct);
  k3_pv<<<512, 512, 0, stream>>>(Sp, encT, fct, out);
}

// Round 5
// 207.487 us; speedup vs baseline: 1.1375x; 1.1375x over previous
//
#include <hip/hip_runtime.h>
#include <cstdint>
#include <cstddef>

#define Bb 8
#define Ss 2048
#define Dd 512

typedef _Float16 half8 __attribute__((ext_vector_type(8)));
typedef _Float16 half4_ __attribute__((ext_vector_type(4)));
typedef _Float16 half2_t __attribute__((ext_vector_type(2)));
typedef float f32x4 __attribute__((ext_vector_type(4)));

static __device__ __forceinline__ void gload_lds16(const void* g, void* l) {
  __builtin_amdgcn_global_load_lds((const __attribute__((address_space(1))) void*)g,
                                   (__attribute__((address_space(3))) void*)l,
                                   16, 0, 0);
}

// ---------------- K0: fused prep ----------------
// Each of 8192 blocks: (a) one 32x32 enc tile -> enc16 + encT (LDS transpose),
// (b) one 1024-float chunk of dec -> dec16.  (was two kernels; saves a launch boundary)
__global__ void k0_prep(const float* __restrict__ enc, const float* __restrict__ dec,
                        _Float16* __restrict__ enc16, _Float16* __restrict__ encT,
                        _Float16* __restrict__ dec16) {
  __shared__ float tile[32][33];
  int bid = blockIdx.x;
  int b = bid & 7, kt = (bid >> 3) & 63, dt = bid >> 9;  // 8 * 64 * 16 = 8192 blocks
  int key0 = kt * 32, d0 = dt * 32;
  int t = threadIdx.x;

  // (b) dec convert: 1024 floats per block, 4 per thread
  {
    size_t off = (size_t)bid * 1024 + (size_t)t * 4;
    float4 a = *(const float4*)(dec + off);
    half4_ h;
    h[0] = (_Float16)a.x; h[1] = (_Float16)a.y; h[2] = (_Float16)a.z; h[3] = (_Float16)a.w;
    *(half4_*)(dec16 + off) = h;
  }

  // (a) enc tile
  const float* src = enc + ((size_t)b * Ss + key0) * Dd + d0;
  _Float16* dst = enc16 + ((size_t)b * Ss + key0) * Dd + d0;
#pragma unroll
  for (int p = 0; p < 4; ++p) {
    int idx = t + p * 256;
    int r = idx >> 5, c = idx & 31;
    float v = src[(size_t)r * Dd + c];
    tile[r][c] = v;
    dst[(size_t)r * Dd + c] = (_Float16)v;
  }
  __syncthreads();
  {
    int dr = t >> 3, kq = t & 7;  // 32 d-rows x 8 key-quads
    _Float16* o = encT + ((size_t)b * Dd + d0 + dr) * Ss + key0 + kq * 4;
    half4_ v;
#pragma unroll
    for (int j = 0; j < 4; ++j) v[j] = (_Float16)tile[kq * 4 + j][dr];
    *(half4_*)o = v;
  }
}

// ---------------- K1: e = exp(dec16 @ enc16^T - m_chunk) + chunk stats ----------------
// (256,2): R4 showed (256,4) doubles FETCH/WRITE via L2 thrash -> keep 2 blocks/CU.
__launch_bounds__(256, 2)
__global__ void k1_qk(const _Float16* __restrict__ A, const _Float16* __restrict__ Bm,
                      _Float16* __restrict__ S, half2_t* __restrict__ pms) {
  __shared__ __align__(16) _Float16 lA[128 * 64];
  __shared__ __align__(16) _Float16 lB[128 * 64];
  int bid = blockIdx.x;
  int b = bid & 7;
  int t = bid >> 3;
  int tm = t & 15, tn = t >> 4;  // 16 x 16 tiles of 128
  int tid = threadIdx.x;
  int w = tid >> 6, L = tid & 63;
  int wm = w & 1, wn = w >> 1;

  const _Float16* Ag = A + ((size_t)b * Ss + (size_t)tm * 128) * Dd;
  const _Float16* Bg = Bm + ((size_t)b * Ss + (size_t)tn * 128) * Dd;

  int rowS[4], colS[4], ldsOff[4];
#pragma unroll
  for (int i = 0; i < 4; ++i) {
    int se = (w * 4 + i) * 512 + L * 8;  // linear f16 slot
    int row = se >> 6;
    int blk = (se >> 3) & 7;
    rowS[i] = row;
    colS[i] = (blk ^ (row & 7)) << 3;
    ldsOff[i] = se;
  }

  f32x4 acc[4][4];
#pragma unroll
  for (int mt = 0; mt < 4; ++mt)
#pragma unroll
    for (int nt = 0; nt < 4; ++nt) acc[mt][nt] = (f32x4){0.f, 0.f, 0.f, 0.f};

  int g = L >> 4, lm = L & 15;

  for (int k0 = 0; k0 < Dd; k0 += 64) {
    __syncthreads();
#pragma unroll
    for (int i = 0; i < 4; ++i) {
      gload_lds16(Ag + (size_t)rowS[i] * Dd + k0 + colS[i], lA + ldsOff[i]);
      gload_lds16(Bg + (size_t)rowS[i] * Dd + k0 + colS[i], lB + ldsOff[i]);
    }
    __syncthreads();
#pragma unroll
    for (int ds = 0; ds < 64; ds += 32) {
      half8 af[4], bf[4];
#pragma unroll
      for (int mt = 0; mt < 4; ++mt) {
        int row = wm * 64 + mt * 16 + lm;
        int blk = ((ds >> 3) + g) ^ (row & 7);
        af[mt] = *(const half8*)(lA + row * 64 + blk * 8);
      }
#pragma unroll
      for (int nt = 0; nt < 4; ++nt) {
        int row = wn * 64 + nt * 16 + lm;
        int blk = ((ds >> 3) + g) ^ (row & 7);
        bf[nt] = *(const half8*)(lB + row * 64 + blk * 8);
      }
#pragma unroll
      for (int mt = 0; mt < 4; ++mt)
#pragma unroll
        for (int nt = 0; nt < 4; ++nt)
          acc[mt][nt] = __builtin_amdgcn_mfma_f32_16x16x32_f16(af[mt], bf[nt], acc[mt][nt], 0, 0, 0);
    }
  }

  // epilogue: per (row, 64-col chunk) max + exp + sum; store e = exp(s - m_c) as f16
  size_t rowbase = (size_t)b * Ss;
#pragma unroll
  for (int mt = 0; mt < 4; ++mt) {
#pragma unroll
    for (int r = 0; r < 4; ++r) {
      int row_g = tm * 128 + wm * 64 + mt * 16 + g * 4 + r;
      _Float16* Srow = S + (rowbase + row_g) * Ss + (size_t)tn * 128 + wn * 64 + lm;
      float rm = -1e30f;
#pragma unroll
      for (int nt = 0; nt < 4; ++nt) rm = fmaxf(rm, acc[mt][nt][r]);
      rm = fmaxf(rm, __shfl_xor(rm, 1));
      rm = fmaxf(rm, __shfl_xor(rm, 2));
      rm = fmaxf(rm, __shfl_xor(rm, 4));
      rm = fmaxf(rm, __shfl_xor(rm, 8));
      _Float16 mh = (_Float16)rm;   // f16-rounded chunk max; SAME value re-derived in k3 prologue
      float mf = (float)mh;
      float sum = 0.f;
#pragma unroll
      for (int nt = 0; nt < 4; ++nt) {
        float e = __expf(acc[mt][nt][r] - mf);
        Srow[nt * 16] = (_Float16)e;
        sum += e;
      }
      sum += __shfl_xor(sum, 1);
      sum += __shfl_xor(sum, 2);
      sum += __shfl_xor(sum, 4);
      sum += __shfl_xor(sum, 8);
      if (lm == 0) {
        half2_t st; st.x = mh; st.y = (_Float16)sum;
        pms[(rowbase + row_g) * 32 + tn * 2 + wn] = st;
      }
    }
  }
}

// ---------------- K3: C = (e .* factor) @ V, factors computed in-block from pms ----------------
// Prologue: threads 0..127 each reduce one row's 32 chunk stats -> fctL[chunk][row] in LDS.
// K-loop: af scaled in-register by LDS-resident per-chunk factor (v_pk_mul_f16, overlaps MFMA).
__launch_bounds__(256, 2)
__global__ void k3_pv(const _Float16* __restrict__ P, const _Float16* __restrict__ Vt,
                      const half2_t* __restrict__ pms, float* __restrict__ C) {
  __shared__ __align__(16) _Float16 lA[128 * 64];
  __shared__ __align__(16) _Float16 lB[128 * 64];
  __shared__ float fctL[32 * 128];  // [chunk][row] 16 KB
  int bid = blockIdx.x;
  int b = bid & 7;
  int t = bid >> 3;
  int tm = t & 15, tn = t >> 4;  // 16 m-tiles, 4 n-tiles
  int tid = threadIdx.x;
  int w = tid >> 6, L = tid & 63;
  int wm = w & 1, wn = w >> 1;

  // ---- prologue: per-row softmax factors for this block's 128 rows ----
  if (tid < 128) {
    const half2_t* pr = pms + ((size_t)b * Ss + (size_t)tm * 128 + tid) * 32;
    float mc[32], sc[32];
#pragma unroll
    for (int c = 0; c < 32; ++c) { half2_t v = pr[c]; mc[c] = (float)v.x; sc[c] = (float)v.y; }
    float m = mc[0];
#pragma unroll
    for (int c = 1; c < 32; ++c) m = fmaxf(m, mc[c]);
    float tot = 0.f;
    float ef[32];
#pragma unroll
    for (int c = 0; c < 32; ++c) { ef[c] = __expf(mc[c] - m); tot += sc[c] * ef[c]; }
    float rinv = 1.0f / tot;
#pragma unroll
    for (int c = 0; c < 32; ++c) fctL[c * 128 + tid] = ef[c] * rinv;
  }

  const _Float16* Ag = P + ((size_t)b * Ss + (size_t)tm * 128) * Ss;   // pitch 2048
  const _Float16* Bg = Vt + ((size_t)b * Dd + (size_t)tn * 128) * Ss;  // pitch 2048

  int rowS[4], colS[4], ldsOff[4];
#pragma unroll
  for (int i = 0; i < 4; ++i) {
    int se = (w * 4 + i) * 512 + L * 8;
    int row = se >> 6;
    int blk = (se >> 3) & 7;
    rowS[i] = row;
    colS[i] = (blk ^ (row & 7)) << 3;
    ldsOff[i] = se;
  }

  f32x4 acc[4][4];
#pragma unroll
  for (int mt = 0; mt < 4; ++mt)
#pragma unroll
    for (int nt = 0; nt < 4; ++nt) acc[mt][nt] = (f32x4){0.f, 0.f, 0.f, 0.f};

  int g = L >> 4, lm = L & 15;

  for (int k0 = 0; k0 < Ss; k0 += 64) {
    __syncthreads();
#pragma unroll
    for (int i = 0; i < 4; ++i) {
      gload_lds16(Ag + (size_t)rowS[i] * Ss + k0 + colS[i], lA + ldsOff[i]);
      gload_lds16(Bg + (size_t)rowS[i] * Ss + k0 + colS[i], lB + ldsOff[i]);
    }
    __syncthreads();
    // per-chunk factors for this k0, from LDS (conflict-free: consecutive lm -> consecutive banks)
    _Float16 fh[4];
#pragma unroll
    for (int mt = 0; mt < 4; ++mt)
      fh[mt] = (_Float16)fctL[(k0 >> 6) * 128 + wm * 64 + mt * 16 + lm];
#pragma unroll
    for (int ds = 0; ds < 64; ds += 32) {
      half8 af[4], bf[4];
#pragma unroll
      for (int mt = 0; mt < 4; ++mt) {
        int row = wm * 64 + mt * 16 + lm;
        int blk = ((ds >> 3) + g) ^ (row & 7);
        af[mt] = *(const half8*)(lA + row * 64 + blk * 8);
#pragma unroll
        for (int j = 0; j < 8; ++j) af[mt][j] *= fh[mt];
      }
#pragma unroll
      for (int nt = 0; nt < 4; ++nt) {
        int row = wn * 64 + nt * 16 + lm;
        int blk = ((ds >> 3) + g) ^ (row & 7);
        bf[nt] = *(const half8*)(lB + row * 64 + blk * 8);
      }
#pragma unroll
      for (int mt = 0; mt < 4; ++mt)
#pragma unroll
        for (int nt = 0; nt < 4; ++nt)
          acc[mt][nt] = __builtin_amdgcn_mfma_f32_16x16x32_f16(af[mt], bf[nt], acc[mt][nt], 0, 0, 0);
    }
  }

  // epilogue: fp32 store to output
#pragma unroll
  for (int mt = 0; mt < 4; ++mt) {
#pragma unroll
    for (int r = 0; r < 4; ++r) {
      int row_g = tm * 128 + wm * 64 + mt * 16 + g * 4 + r;
      float* Crow = C + ((size_t)b * Ss + row_g) * Dd + (size_t)tn * 128 + wn * 64 + lm;
#pragma unroll
      for (int nt = 0; nt < 4; ++nt) Crow[nt * 16] = acc[mt][nt][r];
    }
  }
}

extern "C" void kernel_launch(void* const* d_in, const int* in_sizes, int n_in,
                              void* d_out, int out_size, void* d_ws, size_t ws_size,
                              hipStream_t stream) {
  const float* enc = (const float*)d_in[0];  // enc_outputs [8][2048][512]
  const float* dec = (const float*)d_in[1];  // dec_outputs [8][2048][512]
  float* out = (float*)d_out;                // [8][2048][512] fp32

  const size_t nElem = (size_t)Bb * Ss * Dd;  // 8388608
  const size_t nS = (size_t)Bb * Ss * Ss;     // 33554432

  _Float16* dec16 = (_Float16*)d_ws;
  _Float16* enc16 = dec16 + nElem;
  _Float16* encT = enc16 + nElem;
  _Float16* Sp = encT + nElem;
  half2_t* pms = (half2_t*)(Sp + nS);         // [16384 rows][32 chunks] half2 = 2 MB

  size_t need = nElem * 2 * 3 + nS * 2 + (size_t)Bb * Ss * 32 * 4;
  if (ws_size < need) return;

  k0_prep<<<8192, 256, 0, stream>>>(enc, dec, enc16, encT, dec16);
  k1_qk<<<2048, 256, 0, stream>>>(dec16, enc16, Sp, pms);
  k3_pv<<<512, 256, 0, stream>>>(Sp, encT, pms, out);
}

// Round 6
// 197.906 us; speedup vs baseline: 1.1925x; 1.0484x over previous
//
#include <hip/hip_runtime.h>
#include <cstdint>
#include <cstddef>

#define Bb 8
#define Ss 2048
#define Dd 512

typedef _Float16 half8 __attribute__((ext_vector_type(8)));
typedef _Float16 half4_ __attribute__((ext_vector_type(4)));
typedef _Float16 half2_t __attribute__((ext_vector_type(2)));
typedef float f32x4 __attribute__((ext_vector_type(4)));

static __device__ __forceinline__ void gload_lds16(const void* g, void* l) {
  __builtin_amdgcn_global_load_lds((const __attribute__((address_space(1))) void*)g,
                                   (__attribute__((address_space(3))) void*)l,
                                   16, 0, 0);
}

// ---------------- K0: fused prep, v2 (coalescing-first) ----------------
// 2048 blocks x 256 thr. Per block: one 64(key) x 64(d) enc tile -> enc16 (direct
// from registers, 128B runs) + encT (LDS [K][d][k] layout: b128 conflict-free reads,
// 128B-run global stores); plus 4096 dec floats -> dec16 (fully coalesced).
__global__ void k0_prep(const float* __restrict__ enc, const float* __restrict__ dec,
                        _Float16* __restrict__ enc16, _Float16* __restrict__ encT,
                        _Float16* __restrict__ dec16) {
  __shared__ _Float16 tb[8][64][8];  // [key>>3][d][key&7], 8 KB
  int bid = blockIdx.x;
  int b = bid & 7, kt = (bid >> 3) & 31, dt = bid >> 8;  // 8*32*8 = 2048
  int key0 = kt * 64, d0 = dt * 64;
  int t = threadIdx.x;

  // dec convert: 4096 floats/block, 16/thread, fully coalesced
  {
    size_t off = (size_t)bid * 4096 + (size_t)t * 16;
    const float4* p = (const float4*)(dec + off);
    float4 a0 = p[0], a1 = p[1], a2 = p[2], a3 = p[3];
    half8 h0, h1;
    h0[0] = (_Float16)a0.x; h0[1] = (_Float16)a0.y; h0[2] = (_Float16)a0.z; h0[3] = (_Float16)a0.w;
    h0[4] = (_Float16)a1.x; h0[5] = (_Float16)a1.y; h0[6] = (_Float16)a1.z; h0[7] = (_Float16)a1.w;
    h1[0] = (_Float16)a2.x; h1[1] = (_Float16)a2.y; h1[2] = (_Float16)a2.z; h1[3] = (_Float16)a2.w;
    h1[4] = (_Float16)a3.x; h1[5] = (_Float16)a3.y; h1[6] = (_Float16)a3.z; h1[7] = (_Float16)a3.w;
    *(half8*)(dec16 + off) = h0;
    *(half8*)(dec16 + off + 8) = h1;
  }

  // enc tile: load float4 (256B runs), store enc16 half4 direct, scatter f16 into tb
  const float* src = enc + ((size_t)b * Ss + key0) * Dd + d0;
  _Float16* d16 = enc16 + ((size_t)b * Ss + key0) * Dd + d0;
#pragma unroll
  for (int p = 0; p < 4; ++p) {
    int row = p * 16 + (t >> 4);  // key within tile (0..63)
    int c = (t & 15) * 4;         // d within tile
    float4 a = *(const float4*)(src + (size_t)row * Dd + c);
    half4_ h;
    h[0] = (_Float16)a.x; h[1] = (_Float16)a.y; h[2] = (_Float16)a.z; h[3] = (_Float16)a.w;
    *(half4_*)(d16 + (size_t)row * Dd + c) = h;
    int K = row >> 3, k = row & 7;
#pragma unroll
    for (int i = 0; i < 4; ++i) tb[K][c + i][k] = h[i];
  }
  __syncthreads();

  // encT write-out: per thread 2x half8 (contiguous LDS read, 128B-run global store)
  _Float16* oT = encT + ((size_t)b * Dd + d0) * Ss + key0;
#pragma unroll
  for (int q = 0; q < 2; ++q) {
    int d = q * 32 + (t >> 3);  // 0..63
    int k8 = (t & 7) * 8;
    half8 v = *(const half8*)&tb[k8 >> 3][d][0];
    *(half8*)(oT + (size_t)d * Ss + k8) = v;
  }
}

// ---------------- K1: e = exp(dec16 @ enc16^T - m_chunk) + chunk stats ----------------
// (256,2): R4 showed (256,4) doubles FETCH/WRITE via L2 thrash -> keep 2 blocks/CU.
__launch_bounds__(256, 2)
__global__ void k1_qk(const _Float16* __restrict__ A, const _Float16* __restrict__ Bm,
                      _Float16* __restrict__ S, half2_t* __restrict__ pms) {
  __shared__ __align__(16) _Float16 lA[128 * 64];
  __shared__ __align__(16) _Float16 lB[128 * 64];
  int bid = blockIdx.x;
  int b = bid & 7;
  int t = bid >> 3;
  int tm = t & 15, tn = t >> 4;  // 16 x 16 tiles of 128
  int tid = threadIdx.x;
  int w = tid >> 6, L = tid & 63;
  int wm = w & 1, wn = w >> 1;

  const _Float16* Ag = A + ((size_t)b * Ss + (size_t)tm * 128) * Dd;
  const _Float16* Bg = Bm + ((size_t)b * Ss + (size_t)tn * 128) * Dd;

  int rowS[4], colS[4], ldsOff[4];
#pragma unroll
  for (int i = 0; i < 4; ++i) {
    int se = (w * 4 + i) * 512 + L * 8;  // linear f16 slot
    int row = se >> 6;
    int blk = (se >> 3) & 7;
    rowS[i] = row;
    colS[i] = (blk ^ (row & 7)) << 3;
    ldsOff[i] = se;
  }

  f32x4 acc[4][4];
#pragma unroll
  for (int mt = 0; mt < 4; ++mt)
#pragma unroll
    for (int nt = 0; nt < 4; ++nt) acc[mt][nt] = (f32x4){0.f, 0.f, 0.f, 0.f};

  int g = L >> 4, lm = L & 15;

  for (int k0 = 0; k0 < Dd; k0 += 64) {
    __syncthreads();
#pragma unroll
    for (int i = 0; i < 4; ++i) {
      gload_lds16(Ag + (size_t)rowS[i] * Dd + k0 + colS[i], lA + ldsOff[i]);
      gload_lds16(Bg + (size_t)rowS[i] * Dd + k0 + colS[i], lB + ldsOff[i]);
    }
    __syncthreads();
#pragma unroll
    for (int ds = 0; ds < 64; ds += 32) {
      half8 af[4], bf[4];
#pragma unroll
      for (int mt = 0; mt < 4; ++mt) {
        int row = wm * 64 + mt * 16 + lm;
        int blk = ((ds >> 3) + g) ^ (row & 7);
        af[mt] = *(const half8*)(lA + row * 64 + blk * 8);
      }
#pragma unroll
      for (int nt = 0; nt < 4; ++nt) {
        int row = wn * 64 + nt * 16 + lm;
        int blk = ((ds >> 3) + g) ^ (row & 7);
        bf[nt] = *(const half8*)(lB + row * 64 + blk * 8);
      }
#pragma unroll
      for (int mt = 0; mt < 4; ++mt)
#pragma unroll
        for (int nt = 0; nt < 4; ++nt)
          acc[mt][nt] = __builtin_amdgcn_mfma_f32_16x16x32_f16(af[mt], bf[nt], acc[mt][nt], 0, 0, 0);
    }
  }

  // epilogue: per (row, 64-col chunk) max + exp + sum; store e = exp(s - m_c) as f16
  size_t rowbase = (size_t)b * Ss;
#pragma unroll
  for (int mt = 0; mt < 4; ++mt) {
#pragma unroll
    for (int r = 0; r < 4; ++r) {
      int row_g = tm * 128 + wm * 64 + mt * 16 + g * 4 + r;
      _Float16* Srow = S + (rowbase + row_g) * Ss + (size_t)tn * 128 + wn * 64 + lm;
      float rm = -1e30f;
#pragma unroll
      for (int nt = 0; nt < 4; ++nt) rm = fmaxf(rm, acc[mt][nt][r]);
      rm = fmaxf(rm, __shfl_xor(rm, 1));
      rm = fmaxf(rm, __shfl_xor(rm, 2));
      rm = fmaxf(rm, __shfl_xor(rm, 4));
      rm = fmaxf(rm, __shfl_xor(rm, 8));
      _Float16 mh = (_Float16)rm;   // f16-rounded chunk max; SAME value re-derived in k3 prologue
      float mf = (float)mh;
      float sum = 0.f;
#pragma unroll
      for (int nt = 0; nt < 4; ++nt) {
        float e = __expf(acc[mt][nt][r] - mf);
        Srow[nt * 16] = (_Float16)e;
        sum += e;
      }
      sum += __shfl_xor(sum, 1);
      sum += __shfl_xor(sum, 2);
      sum += __shfl_xor(sum, 4);
      sum += __shfl_xor(sum, 8);
      if (lm == 0) {
        half2_t st; st.x = mh; st.y = (_Float16)sum;
        pms[(rowbase + row_g) * 32 + tn * 2 + wn] = st;
      }
    }
  }
}

// ---------------- K3: C = (e .* factor) @ V, factors computed in-block from pms ----------------
__launch_bounds__(256, 2)
__global__ void k3_pv(const _Float16* __restrict__ P, const _Float16* __restrict__ Vt,
                      const half2_t* __restrict__ pms, float* __restrict__ C) {
  __shared__ __align__(16) _Float16 lA[128 * 64];
  __shared__ __align__(16) _Float16 lB[128 * 64];
  __shared__ float fctL[32 * 128];  // [chunk][row] 16 KB
  int bid = blockIdx.x;
  int b = bid & 7;
  int t = bid >> 3;
  int tm = t & 15, tn = t >> 4;  // 16 m-tiles, 4 n-tiles
  int tid = threadIdx.x;
  int w = tid >> 6, L = tid & 63;
  int wm = w & 1, wn = w >> 1;

  // ---- prologue: per-row softmax factors for this block's 128 rows ----
  if (tid < 128) {
    const half2_t* pr = pms + ((size_t)b * Ss + (size_t)tm * 128 + tid) * 32;
    float mc[32], sc[32];
#pragma unroll
    for (int c = 0; c < 32; ++c) { half2_t v = pr[c]; mc[c] = (float)v.x; sc[c] = (float)v.y; }
    float m = mc[0];
#pragma unroll
    for (int c = 1; c < 32; ++c) m = fmaxf(m, mc[c]);
    float tot = 0.f;
    float ef[32];
#pragma unroll
    for (int c = 0; c < 32; ++c) { ef[c] = __expf(mc[c] - m); tot += sc[c] * ef[c]; }
    float rinv = 1.0f / tot;
#pragma unroll
    for (int c = 0; c < 32; ++c) fctL[c * 128 + tid] = ef[c] * rinv;
  }

  const _Float16* Ag = P + ((size_t)b * Ss + (size_t)tm * 128) * Ss;   // pitch 2048
  const _Float16* Bg = Vt + ((size_t)b * Dd + (size_t)tn * 128) * Ss;  // pitch 2048

  int rowS[4], colS[4], ldsOff[4];
#pragma unroll
  for (int i = 0; i < 4; ++i) {
    int se = (w * 4 + i) * 512 + L * 8;
    int row = se >> 6;
    int blk = (se >> 3) & 7;
    rowS[i] = row;
    colS[i] = (blk ^ (row & 7)) << 3;
    ldsOff[i] = se;
  }

  f32x4 acc[4][4];
#pragma unroll
  for (int mt = 0; mt < 4; ++mt)
#pragma unroll
    for (int nt = 0; nt < 4; ++nt) acc[mt][nt] = (f32x4){0.f, 0.f, 0.f, 0.f};

  int g = L >> 4, lm = L & 15;

  for (int k0 = 0; k0 < Ss; k0 += 64) {
    __syncthreads();
#pragma unroll
    for (int i = 0; i < 4; ++i) {
      gload_lds16(Ag + (size_t)rowS[i] * Ss + k0 + colS[i], lA + ldsOff[i]);
      gload_lds16(Bg + (size_t)rowS[i] * Ss + k0 + colS[i], lB + ldsOff[i]);
    }
    __syncthreads();
    _Float16 fh[4];
#pragma unroll
    for (int mt = 0; mt < 4; ++mt)
      fh[mt] = (_Float16)fctL[(k0 >> 6) * 128 + wm * 64 + mt * 16 + lm];
#pragma unroll
    for (int ds = 0; ds < 64; ds += 32) {
      half8 af[4], bf[4];
#pragma unroll
      for (int mt = 0; mt < 4; ++mt) {
        int row = wm * 64 + mt * 16 + lm;
        int blk = ((ds >> 3) + g) ^ (row & 7);
        af[mt] = *(const half8*)(lA + row * 64 + blk * 8);
#pragma unroll
        for (int j = 0; j < 8; ++j) af[mt][j] *= fh[mt];
      }
#pragma unroll
      for (int nt = 0; nt < 4; ++nt) {
        int row = wn * 64 + nt * 16 + lm;
        int blk = ((ds >> 3) + g) ^ (row & 7);
        bf[nt] = *(const half8*)(lB + row * 64 + blk * 8);
      }
#pragma unroll
      for (int mt = 0; mt < 4; ++mt)
#pragma unroll
        for (int nt = 0; nt < 4; ++nt)
          acc[mt][nt] = __builtin_amdgcn_mfma_f32_16x16x32_f16(af[mt], bf[nt], acc[mt][nt], 0, 0, 0);
    }
  }

  // epilogue: fp32 store to output
#pragma unroll
  for (int mt = 0; mt < 4; ++mt) {
#pragma unroll
    for (int r = 0; r < 4; ++r) {
      int row_g = tm * 128 + wm * 64 + mt * 16 + g * 4 + r;
      float* Crow = C + ((size_t)b * Ss + row_g) * Dd + (size_t)tn * 128 + wn * 64 + lm;
#pragma unroll
      for (int nt = 0; nt < 4; ++nt) Crow[nt * 16] = acc[mt][nt][r];
    }
  }
}

extern "C" void kernel_launch(void* const* d_in, const int* in_sizes, int n_in,
                              void* d_out, int out_size, void* d_ws, size_t ws_size,
                              hipStream_t stream) {
  const float* enc = (const float*)d_in[0];  // enc_outputs [8][2048][512]
  const float* dec = (const float*)d_in[1];  // dec_outputs [8][2048][512]
  float* out = (float*)d_out;                // [8][2048][512] fp32

  const size_t nElem = (size_t)Bb * Ss * Dd;  // 8388608
  const size_t nS = (size_t)Bb * Ss * Ss;     // 33554432

  _Float16* dec16 = (_Float16*)d_ws;
  _Float16* enc16 = dec16 + nElem;
  _Float16* encT = enc16 + nElem;
  _Float16* Sp = encT + nElem;
  half2_t* pms = (half2_t*)(Sp + nS);         // [16384 rows][32 chunks] half2 = 2 MB

  size_t need = nElem * 2 * 3 + nS * 2 + (size_t)Bb * Ss * 32 * 4;
  if (ws_size < need) return;

  k0_prep<<<2048, 256, 0, stream>>>(enc, dec, enc16, encT, dec16);
  k1_qk<<<2048, 256, 0, stream>>>(dec16, enc16, Sp, pms);
  k3_pv<<<512, 256, 0, stream>>>(Sp, encT, pms, out);
}

// Round 7
// 196.648 us; speedup vs baseline: 1.2002x; 1.0064x over previous
//
#include <hip/hip_runtime.h>
#include <cstdint>
#include <cstddef>

#define Bb 8
#define Ss 2048
#define Dd 512

typedef _Float16 half8 __attribute__((ext_vector_type(8)));
typedef _Float16 half4_ __attribute__((ext_vector_type(4)));
typedef _Float16 half2_t __attribute__((ext_vector_type(2)));
typedef float f32x4 __attribute__((ext_vector_type(4)));

static __device__ __forceinline__ void gload_lds16(const void* g, void* l) {
  __builtin_amdgcn_global_load_lds((const __attribute__((address_space(1))) void*)g,
                                   (__attribute__((address_space(3))) void*)l,
                                   16, 0, 0);
}

// ---------------- K0: fused prep, v2 (coalescing-first) ----------------
__global__ void k0_prep(const float* __restrict__ enc, const float* __restrict__ dec,
                        _Float16* __restrict__ enc16, _Float16* __restrict__ encT,
                        _Float16* __restrict__ dec16) {
  __shared__ _Float16 tb[8][64][8];  // [key>>3][d][key&7], 8 KB
  int bid = blockIdx.x;
  int b = bid & 7, kt = (bid >> 3) & 31, dt = bid >> 8;  // 8*32*8 = 2048
  int key0 = kt * 64, d0 = dt * 64;
  int t = threadIdx.x;

  // dec convert: 4096 floats/block, 16/thread, fully coalesced
  {
    size_t off = (size_t)bid * 4096 + (size_t)t * 16;
    const float4* p = (const float4*)(dec + off);
    float4 a0 = p[0], a1 = p[1], a2 = p[2], a3 = p[3];
    half8 h0, h1;
    h0[0] = (_Float16)a0.x; h0[1] = (_Float16)a0.y; h0[2] = (_Float16)a0.z; h0[3] = (_Float16)a0.w;
    h0[4] = (_Float16)a1.x; h0[5] = (_Float16)a1.y; h0[6] = (_Float16)a1.z; h0[7] = (_Float16)a1.w;
    h1[0] = (_Float16)a2.x; h1[1] = (_Float16)a2.y; h1[2] = (_Float16)a2.z; h1[3] = (_Float16)a2.w;
    h1[4] = (_Float16)a3.x; h1[5] = (_Float16)a3.y; h1[6] = (_Float16)a3.z; h1[7] = (_Float16)a3.w;
    *(half8*)(dec16 + off) = h0;
    *(half8*)(dec16 + off + 8) = h1;
  }

  // enc tile: load float4 (256B runs), store enc16 half4 direct, scatter f16 into tb
  const float* src = enc + ((size_t)b * Ss + key0) * Dd + d0;
  _Float16* d16 = enc16 + ((size_t)b * Ss + key0) * Dd + d0;
#pragma unroll
  for (int p = 0; p < 4; ++p) {
    int row = p * 16 + (t >> 4);  // key within tile (0..63)
    int c = (t & 15) * 4;         // d within tile
    float4 a = *(const float4*)(src + (size_t)row * Dd + c);
    half4_ h;
    h[0] = (_Float16)a.x; h[1] = (_Float16)a.y; h[2] = (_Float16)a.z; h[3] = (_Float16)a.w;
    *(half4_*)(d16 + (size_t)row * Dd + c) = h;
    int K = row >> 3, k = row & 7;
#pragma unroll
    for (int i = 0; i < 4; ++i) tb[K][c + i][k] = h[i];
  }
  __syncthreads();

  // encT write-out: per thread 2x half8 (contiguous LDS read, 128B-run global store)
  _Float16* oT = encT + ((size_t)b * Dd + d0) * Ss + key0;
#pragma unroll
  for (int q = 0; q < 2; ++q) {
    int d = q * 32 + (t >> 3);  // 0..63
    int k8 = (t & 7) * 8;
    half8 v = *(const half8*)&tb[k8 >> 3][d][0];
    *(half8*)(oT + (size_t)d * Ss + k8) = v;
  }
}

// ---------------- K1: e = exp(dec16 @ enc16^T - m_chunk) + chunk stats ----------------
// (256,2): R4 showed (256,4) doubles FETCH/WRITE via L2 write thrash -> keep 2 blocks/CU.
__launch_bounds__(256, 2)
__global__ void k1_qk(const _Float16* __restrict__ A, const _Float16* __restrict__ Bm,
                      _Float16* __restrict__ S, half2_t* __restrict__ pms) {
  __shared__ __align__(16) _Float16 lA[128 * 64];
  __shared__ __align__(16) _Float16 lB[128 * 64];
  int bid = blockIdx.x;
  int b = bid & 7;
  int t = bid >> 3;
  int tm = t & 15, tn = t >> 4;  // 16 x 16 tiles of 128
  int tid = threadIdx.x;
  int w = tid >> 6, L = tid & 63;
  int wm = w & 1, wn = w >> 1;

  const _Float16* Ag = A + ((size_t)b * Ss + (size_t)tm * 128) * Dd;
  const _Float16* Bg = Bm + ((size_t)b * Ss + (size_t)tn * 128) * Dd;

  int rowS[4], colS[4], ldsOff[4];
#pragma unroll
  for (int i = 0; i < 4; ++i) {
    int se = (w * 4 + i) * 512 + L * 8;  // linear f16 slot
    int row = se >> 6;
    int blk = (se >> 3) & 7;
    rowS[i] = row;
    colS[i] = (blk ^ (row & 7)) << 3;
    ldsOff[i] = se;
  }

  f32x4 acc[4][4];
#pragma unroll
  for (int mt = 0; mt < 4; ++mt)
#pragma unroll
    for (int nt = 0; nt < 4; ++nt) acc[mt][nt] = (f32x4){0.f, 0.f, 0.f, 0.f};

  int g = L >> 4, lm = L & 15;

  for (int k0 = 0; k0 < Dd; k0 += 64) {
    __syncthreads();
#pragma unroll
    for (int i = 0; i < 4; ++i) {
      gload_lds16(Ag + (size_t)rowS[i] * Dd + k0 + colS[i], lA + ldsOff[i]);
      gload_lds16(Bg + (size_t)rowS[i] * Dd + k0 + colS[i], lB + ldsOff[i]);
    }
    __syncthreads();
#pragma unroll
    for (int ds = 0; ds < 64; ds += 32) {
      half8 af[4], bf[4];
#pragma unroll
      for (int mt = 0; mt < 4; ++mt) {
        int row = wm * 64 + mt * 16 + lm;
        int blk = ((ds >> 3) + g) ^ (row & 7);
        af[mt] = *(const half8*)(lA + row * 64 + blk * 8);
      }
#pragma unroll
      for (int nt = 0; nt < 4; ++nt) {
        int row = wn * 64 + nt * 16 + lm;
        int blk = ((ds >> 3) + g) ^ (row & 7);
        bf[nt] = *(const half8*)(lB + row * 64 + blk * 8);
      }
#pragma unroll
      for (int mt = 0; mt < 4; ++mt)
#pragma unroll
        for (int nt = 0; nt < 4; ++nt)
          acc[mt][nt] = __builtin_amdgcn_mfma_f32_16x16x32_f16(af[mt], bf[nt], acc[mt][nt], 0, 0, 0);
    }
  }

  // epilogue: per (row, 64-col chunk) max + exp + sum; store e = exp(s - m_c) as f16
  size_t rowbase = (size_t)b * Ss;
#pragma unroll
  for (int mt = 0; mt < 4; ++mt) {
#pragma unroll
    for (int r = 0; r < 4; ++r) {
      int row_g = tm * 128 + wm * 64 + mt * 16 + g * 4 + r;
      _Float16* Srow = S + (rowbase + row_g) * Ss + (size_t)tn * 128 + wn * 64 + lm;
      float rm = -1e30f;
#pragma unroll
      for (int nt = 0; nt < 4; ++nt) rm = fmaxf(rm, acc[mt][nt][r]);
      rm = fmaxf(rm, __shfl_xor(rm, 1));
      rm = fmaxf(rm, __shfl_xor(rm, 2));
      rm = fmaxf(rm, __shfl_xor(rm, 4));
      rm = fmaxf(rm, __shfl_xor(rm, 8));
      _Float16 mh = (_Float16)rm;   // f16-rounded chunk max; SAME value re-derived in k3 prologue
      float mf = (float)mh;
      float sum = 0.f;
#pragma unroll
      for (int nt = 0; nt < 4; ++nt) {
        float e = __expf(acc[mt][nt][r] - mf);
        Srow[nt * 16] = (_Float16)e;
        sum += e;
      }
      sum += __shfl_xor(sum, 1);
      sum += __shfl_xor(sum, 2);
      sum += __shfl_xor(sum, 4);
      sum += __shfl_xor(sum, 8);
      if (lm == 0) {
        half2_t st; st.x = mh; st.y = (_Float16)sum;
        pms[(rowbase + row_g) * 32 + tn * 2 + wn] = st;
      }
    }
  }
}

// ---------------- K3: C = (e .* factor) @ V  — 128x64 tiles for occupancy ----------------
// Grid 1024 (8b x 16tm x 8tn), LDS 40 KB (lA 16K + lB 8K + fctL 16K) -> exactly 4 blocks/CU,
// 16 waves/CU (2x the old 512-block config). acc 4x2 (32 AGPR), 60+32=92 regs < 128 cap @ 4 w/SIMD.
__launch_bounds__(256, 4)
__global__ void k3_pv(const _Float16* __restrict__ P, const _Float16* __restrict__ Vt,
                      const half2_t* __restrict__ pms, float* __restrict__ C) {
  __shared__ __align__(16) _Float16 lA[128 * 64];
  __shared__ __align__(16) _Float16 lB[64 * 64];
  __shared__ float fctL[32 * 128];  // [chunk][row] 16 KB
  int bid = blockIdx.x;
  int b = bid & 7;
  int t = bid >> 3;
  int tm = t & 15, tn = t >> 4;  // 16 m-tiles (128), 8 n-tiles (64)
  int tid = threadIdx.x;
  int w = tid >> 6, L = tid & 63;
  int wm = w & 1, wn = w >> 1;   // wn 0..1: 32-col halves of the 64-wide tile

  // ---- prologue: per-row softmax factors for this block's 128 rows ----
  if (tid < 128) {
    const half2_t* pr = pms + ((size_t)b * Ss + (size_t)tm * 128 + tid) * 32;
    float mc[32], sc[32];
#pragma unroll
    for (int c = 0; c < 32; ++c) { half2_t v = pr[c]; mc[c] = (float)v.x; sc[c] = (float)v.y; }
    float m = mc[0];
#pragma unroll
    for (int c = 1; c < 32; ++c) m = fmaxf(m, mc[c]);
    float tot = 0.f;
    float ef[32];
#pragma unroll
    for (int c = 0; c < 32; ++c) { ef[c] = __expf(mc[c] - m); tot += sc[c] * ef[c]; }
    float rinv = 1.0f / tot;
#pragma unroll
    for (int c = 0; c < 32; ++c) fctL[c * 128 + tid] = ef[c] * rinv;
  }

  const _Float16* Ag = P + ((size_t)b * Ss + (size_t)tm * 128) * Ss;   // pitch 2048
  const _Float16* Bg = Vt + ((size_t)b * Dd + (size_t)tn * 64) * Ss;   // pitch 2048

  // lA staging: 4 rounds x 256 thr x 16B = 16 KB
  int rowA[4], colA[4], offA[4];
#pragma unroll
  for (int i = 0; i < 4; ++i) {
    int se = (w * 4 + i) * 512 + L * 8;
    int row = se >> 6;
    int blk = (se >> 3) & 7;
    rowA[i] = row;
    colA[i] = (blk ^ (row & 7)) << 3;
    offA[i] = se;
  }
  // lB staging: 2 rounds x 256 thr x 16B = 8 KB
  int rowB[2], colB[2], offB[2];
#pragma unroll
  for (int i = 0; i < 2; ++i) {
    int se = (w * 2 + i) * 512 + L * 8;
    int row = se >> 6;
    int blk = (se >> 3) & 7;
    rowB[i] = row;
    colB[i] = (blk ^ (row & 7)) << 3;
    offB[i] = se;
  }

  f32x4 acc[4][2];
#pragma unroll
  for (int mt = 0; mt < 4; ++mt)
#pragma unroll
    for (int nt = 0; nt < 2; ++nt) acc[mt][nt] = (f32x4){0.f, 0.f, 0.f, 0.f};

  int g = L >> 4, lm = L & 15;

  for (int k0 = 0; k0 < Ss; k0 += 64) {
    __syncthreads();
#pragma unroll
    for (int i = 0; i < 4; ++i)
      gload_lds16(Ag + (size_t)rowA[i] * Ss + k0 + colA[i], lA + offA[i]);
#pragma unroll
    for (int i = 0; i < 2; ++i)
      gload_lds16(Bg + (size_t)rowB[i] * Ss + k0 + colB[i], lB + offB[i]);
    __syncthreads();
    _Float16 fh[4];
#pragma unroll
    for (int mt = 0; mt < 4; ++mt)
      fh[mt] = (_Float16)fctL[(k0 >> 6) * 128 + wm * 64 + mt * 16 + lm];
#pragma unroll
    for (int ds = 0; ds < 64; ds += 32) {
      half8 af[4], bf[2];
#pragma unroll
      for (int mt = 0; mt < 4; ++mt) {
        int row = wm * 64 + mt * 16 + lm;
        int blk = ((ds >> 3) + g) ^ (row & 7);
        af[mt] = *(const half8*)(lA + row * 64 + blk * 8);
#pragma unroll
        for (int j = 0; j < 8; ++j) af[mt][j] *= fh[mt];
      }
#pragma unroll
      for (int nt = 0; nt < 2; ++nt) {
        int row = wn * 32 + nt * 16 + lm;
        int blk = ((ds >> 3) + g) ^ (row & 7);
        bf[nt] = *(const half8*)(lB + row * 64 + blk * 8);
      }
#pragma unroll
      for (int mt = 0; mt < 4; ++mt)
#pragma unroll
        for (int nt = 0; nt < 2; ++nt)
          acc[mt][nt] = __builtin_amdgcn_mfma_f32_16x16x32_f16(af[mt], bf[nt], acc[mt][nt], 0, 0, 0);
    }
  }

  // epilogue: fp32 store (lanes lm 0..15 -> 64B contiguous runs; 256B-aligned tile rows)
#pragma unroll
  for (int mt = 0; mt < 4; ++mt) {
#pragma unroll
    for (int r = 0; r < 4; ++r) {
      int row_g = tm * 128 + wm * 64 + mt * 16 + g * 4 + r;
      float* Crow = C + ((size_t)b * Ss + row_g) * Dd + (size_t)tn * 64 + wn * 32 + lm;
#pragma unroll
      for (int nt = 0; nt < 2; ++nt) Crow[nt * 16] = acc[mt][nt][r];
    }
  }
}

extern "C" void kernel_launch(void* const* d_in, const int* in_sizes, int n_in,
                              void* d_out, int out_size, void* d_ws, size_t ws_size,
                              hipStream_t stream) {
  const float* enc = (const float*)d_in[0];  // enc_outputs [8][2048][512]
  const float* dec = (const float*)d_in[1];  // dec_outputs [8][2048][512]
  float* out = (float*)d_out;                // [8][2048][512] fp32

  const size_t nElem = (size_t)Bb * Ss * Dd;  // 8388608
  const size_t nS = (size_t)Bb * Ss * Ss;     // 33554432

  _Float16* dec16 = (_Float16*)d_ws;
  _Float16* enc16 = dec16 + nElem;
  _Float16* encT = enc16 + nElem;
  _Float16* Sp = encT + nElem;
  half2_t* pms = (half2_t*)(Sp + nS);         // [16384 rows][32 chunks] half2 = 2 MB

  size_t need = nElem * 2 * 3 + nS * 2 + (size_t)Bb * Ss * 32 * 4;
  if (ws_size < need) return;

  k0_prep<<<2048, 256, 0, stream>>>(enc, dec, enc16, encT, dec16);
  k1_qk<<<2048, 256, 0, stream>>>(dec16, enc16, Sp, pms);
  k3_pv<<<1024, 256, 0, stream>>>(Sp, encT, pms, out);
}